// Round 4
// baseline (297.574 us; speedup 1.0000x reference)
//
#include <hip/hip_runtime.h>
#include <cfloat>
#include <cstddef>

// VQ-VAE vector quantizer, MI355X / gfx950.
// z: (32, 64, 32, 32) f32 BCHW; embedding: (1024, 64) f32.
// Outputs concatenated f32: loss[1], z_q(BCHW)[2097152], perplexity[1],
// min_encodings[32768*1024], min_encoding_indices(as float)[32768].
//
// Structure history (measured):
//   R1 (108us): rows/lane resident, codes via s_load streaming -> 16 waves x
//     disjoint 32KB through 16KB sL1 = thrash, VALUBusy 37%.
//   R2 (284us): codes via per-lane vector loads of uniform addr -> 64x vL1/RF
//     redundancy. Refuted: uniform-address vector loads are not a broadcast.
//   R3 (154us): codes/lane resident, rows via LDS same-addr ds_read_b128 ->
//     broadcast still delivers 16B x 64 lanes = 1KB RF-writes/inst (~8cyc);
//     16 waves re-reading every row = LDS-return-bw bound.
//   R4 (this): codes RESIDENT in VGPRs (2/lane, 8 waves = full codebook);
//     rows streamed on the SCALAR path (s_load, wave-uniform addr) -- the
//     only broadcast on CDNA with no 64x lane replication. All 8 waves read
//     the SAME rows in the same order: sL1 working set ~4KB (64B line = 16
//     consecutive rows of one channel) -> hits after priming. z values feed
//     v_pk_fma_f32 as the single legal scalar operand.
//
// Numerics (bit-exact vs reference; absmax 0.0 through R3):
//   dot: 4 fp32 fma chains (c%4) over k ascending, final (a0+a1)+(a2+a3),
//        via v_pk_fma_f32 pairs (proven bit-exact in R2/R3).
//   e2/z2: sequential double accumulation (ch ascending), rounded once.
//   d = (z2f + e2f) - 2.0f*dot (two fp32 roundings at magnitude ~64).
//   argmin: j = q*128 + 2*lane + s is strictly monotone in (lane,s); in-lane
//   strict < over s, ballot lowest-lane, waves combined ascending -> exact
//   np.argmin first-index tie-break.
//   loss: partial[512] tree kept bit-identical to R1 (two 64-row groups per
//   block, same per-class fma chains, same shfl_down butterfly, same
//   ascending-class sums). vq_final unchanged.

#define NROWS 32768
#define NE    1024
#define EDIM  64
#define RPB   128
#define NBLK  (NROWS / RPB)   // 256 blocks = 1 per CU
#define TPB   512             // 8 waves; lane owns codes j = q*128 + 2*lane + {0,1}
#define NPART 512

#define OFF_LOSS ((size_t)0)
#define OFF_ZQ   ((size_t)1)
#define OFF_PERP ((size_t)2097153)
#define OFF_OH   ((size_t)2097154)
#define OFF_IDX  ((size_t)35651586)

typedef float v2f __attribute__((ext_vector_type(2)));

// ws layout (bytes): [0,4096) int hist[1024]; [4096,6144) float partial[512]

__global__ __launch_bounds__(TPB, 2) void vq_main(const float* __restrict__ z,
                                                  const float* __restrict__ emb,
                                                  int* __restrict__ hist,
                                                  float* __restrict__ partial,
                                                  float* __restrict__ out) {
    const int t    = threadIdx.x;
    const int lane = t & 63;
    const int q    = t >> 6;          // wave id 0..7
    const int r0   = blockIdx.x * RPB;
    const int b    = r0 >> 10;        // 128 | 1024 -> single batch per block
    const int m0   = r0 & 1023;
    const size_t zb0 = (size_t)b * 65536 + (size_t)m0;

    __shared__ float s_z2[RPB];
    __shared__ float s_wd[8][RPB];
    __shared__ int   s_wj[8][RPB];
    __shared__ int   s_idx[RPB];
    __shared__ float s_l2[2][8];

    // ---- resident codebook: lane owns codes jA = q*128+2*lane and jA+1 ----
    const int jA = (q << 7) + (lane << 1);
    float4 cbA[16], cbB[16];
    {
        const float4* eA = (const float4*)(emb + ((size_t)jA << 6));
        const float4* eB = (const float4*)(emb + ((size_t)(jA + 1) << 6));
#pragma unroll
        for (int k = 0; k < 16; ++k) { cbA[k] = eA[k]; cbB[k] = eB[k]; }
    }
    // ||e||^2: sequential double accumulation, ch ascending, one rounding
    float e2A, e2B;
    {
        double sA = 0.0, sB = 0.0;
#pragma unroll
        for (int k = 0; k < 16; ++k) {
            sA += (double)cbA[k].x * (double)cbA[k].x;
            sA += (double)cbA[k].y * (double)cbA[k].y;
            sA += (double)cbA[k].z * (double)cbA[k].z;
            sA += (double)cbA[k].w * (double)cbA[k].w;
            sB += (double)cbB[k].x * (double)cbB[k].x;
            sB += (double)cbB[k].y * (double)cbB[k].y;
            sB += (double)cbB[k].z * (double)cbB[k].z;
            sB += (double)cbB[k].w * (double)cbB[k].w;
        }
        e2A = (float)sA; e2B = (float)sB;
    }

    // ---- ||z_r||^2 per row (double, ch ascending, one rounding) ----------
    if (t < RPB) {
        const float* zr = z + zb0 + t;          // row t, channels stride 1024
        double s = 0.0;
#pragma unroll
        for (int c = 0; c < EDIM; ++c) {
            float v = zr[(size_t)c << 10];
            s += (double)v * (double)v;
        }
        s_z2[t] = (float)s;
    }

    // ---- fire-and-forget zero-fill of this block's one-hot slab ----------
    // 128 rows x 4KB = 512KB contiguous at OFF_OH + r0*1024 (byte %16 == 8).
    // No vmcnt wait exists until the post-scan __syncthreads: the scan is
    // SMEM/DS/VALU only and the mid barrier below waits lgkm only -> these
    // stores drain under ~20+us of scan compute. The post-scan barrier's
    // vmcnt(0) orders the 1.0f scatter after the zeros (as in R1-R3).
    {
        float* ohb = out + OFF_OH + (size_t)r0 * 1024;   // 131072 floats
        if (t == 0) {
            *(float2*)ohb              = make_float2(0.f, 0.f);
            *(float2*)(ohb + 131070)   = make_float2(0.f, 0.f);
        }
        float4* p4 = (float4*)(ohb + 2);                 // 16B-aligned
        const float4 z4 = make_float4(0.f, 0.f, 0.f, 0.f);
        for (int i = t; i < 32767; i += TPB) p4[i] = z4;
    }

    // raw barrier: s_z2 producers flushed (lgkm only) -- zero-fill stores
    // and any other vmem stay in flight through the scan.
    asm volatile("s_waitcnt lgkmcnt(0)" ::: "memory");
    __builtin_amdgcn_s_barrier();

    // ---- scan: rows broadcast via SCALAR loads, codes from VGPRs ----------
    // Address z + zb0 + rb + c*1024 is uniform (blockIdx/loop derived) ->
    // s_load_dword into SGPRs; one SGPR copy per wave, free operand
    // broadcast into v_pk_fma_f32. All waves stream the same rows -> sL1 hit.
    for (int rb = 0; rb < RPB; ++rb) {
        const float* rp = z + zb0 + rb;
        float zl[64];
#pragma unroll
        for (int c = 0; c < EDIM; ++c) zl[c] = rp[(size_t)c << 10];

        v2f a01 = {0.f, 0.f}, a23 = {0.f, 0.f};
        v2f b01 = {0.f, 0.f}, b23 = {0.f, 0.f};
#pragma unroll
        for (int k = 0; k < 16; ++k) {
            v2f zxy = {zl[4 * k + 0], zl[4 * k + 1]};
            v2f zzw = {zl[4 * k + 2], zl[4 * k + 3]};
            v2f eAxy = {cbA[k].x, cbA[k].y}, eAzw = {cbA[k].z, cbA[k].w};
            v2f eBxy = {cbB[k].x, cbB[k].y}, eBzw = {cbB[k].z, cbB[k].w};
            a01 = __builtin_elementwise_fma(eAxy, zxy, a01);  // v_pk_fma_f32
            a23 = __builtin_elementwise_fma(eAzw, zzw, a23);
            b01 = __builtin_elementwise_fma(eBxy, zxy, b01);
            b23 = __builtin_elementwise_fma(eBzw, zzw, b23);
        }
        float dotA = (a01.x + a01.y) + (a23.x + a23.y);
        float dotB = (b01.x + b01.y) + (b23.x + b23.y);
        float z2r  = s_z2[rb];
        float dA   = (z2r + e2A) - 2.0f * dotA;
        float dB   = (z2r + e2B) - 2.0f * dotB;
        // in-lane strict < over s ascending (jA < jB): first index on ties
        int   sl = (dB < dA) ? 1 : 0;
        float dl = (dB < dA) ? dB : dA;
        // wave-wide min value (symmetric butterfly -> all lanes identical)
        float m = dl;
#pragma unroll
        for (int off = 1; off < 64; off <<= 1) m = fminf(m, __shfl_xor(m, off));
        // first-index winner: j monotone in (lane, s) -> lowest lane wins
        unsigned long long bal = __ballot(dl == m);
        int wl = __ffsll((long long)bal) - 1;
        int sw = __shfl(sl, wl);
        int jwin = (q << 7) + (wl << 1) + sw;
        if (lane == 0) { s_wd[q][rb] = m; s_wj[q][rb] = jwin; }
    }
    __syncthreads();   // full barrier: vmcnt(0) -> zero-fill globally visible

    // ---- combine 8 per-wave candidates per row (ascending code chunks) ----
    if (t < RPB) {
        float bd = s_wd[0][t];
        int   bj = s_wj[0][t];
#pragma unroll
        for (int w = 1; w < 8; ++w) {
            float dw = s_wd[w][t];
            if (dw < bd) { bd = dw; bj = s_wj[w][t]; }  // strict <: first index
        }
        s_idx[t] = bj;
        out[OFF_IDX + (size_t)(r0 + t)] = (float)bj;
        out[OFF_OH + (size_t)(r0 + t) * 1024 + bj] = 1.0f;
        atomicAdd(&hist[bj], 1);
    }
    __syncthreads();

    // ---- z_q (straight-through) + loss partials (R1-exact trees) ----------
    // Wave q: row group g = q&1 (rows 64g..64g+63, lane = row), classes
    // c0 = q>>1 and c0+4. Chains, shfl_down butterfly, ascending-class sums
    // identical to R1 -> partial[512] bit-identical; vq_final unchanged.
    {
        const int g   = q & 1;
        const int c0  = q >> 1;
        const int r   = (g << 6) + lane;
        const int grow = r0 + r;
        const int bb  = grow >> 10;
        const int mm  = grow & 1023;
        const size_t zbr = (size_t)bb * 65536 + (size_t)mm;
        const int    jjx = s_idx[r];
        const float* er  = emb + ((size_t)jjx << 6);
        float* zq = out + OFF_ZQ + zbr;
        float lA = 0.f, lB = 0.f;
#pragma unroll
        for (int i = 0; i < 8; ++i) {
            int c = c0 + 8 * i;
            float zc   = z[zbr + (size_t)c * 1024];
            float ev   = er[c];
            float diff = ev - zc;
            zq[(size_t)c * 1024] = zc + diff;           // zp + (z_q - zp)
            lA = fmaf(diff, diff, lA);
        }
#pragma unroll
        for (int i = 0; i < 8; ++i) {
            int c = (c0 + 4) + 8 * i;
            float zc   = z[zbr + (size_t)c * 1024];
            float ev   = er[c];
            float diff = ev - zc;
            zq[(size_t)c * 1024] = zc + diff;
            lB = fmaf(diff, diff, lB);
        }
#pragma unroll
        for (int off = 32; off >= 1; off >>= 1) {
            lA += __shfl_down(lA, off);
            lB += __shfl_down(lB, off);
        }
        if (lane == 0) { s_l2[g][c0] = lA; s_l2[g][c0 + 4] = lB; }
        __syncthreads();
        if (t == 0) {
            float sA = 0.f, sB = 0.f;
#pragma unroll
            for (int c = 0; c < 8; ++c) {   // ascending class, as in R1
                sA += s_l2[0][c];
                sB += s_l2[1][c];
            }
            partial[2 * blockIdx.x + 0] = sA;
            partial[2 * blockIdx.x + 1] = sB;
        }
    }
}

__global__ __launch_bounds__(1024) void vq_final(const int* __restrict__ hist,
                                                 const float* __restrict__ partial,
                                                 float* __restrict__ out) {
    int t = threadIdx.x;
    float p    = (float)hist[t] * (1.0f / 32768.0f);
    float term = p * logf(p + 1e-10f);
    float lp   = (t < NPART) ? partial[t] : 0.f;
#pragma unroll
    for (int off = 32; off >= 1; off >>= 1) {
        term += __shfl_down(term, off);
        lp   += __shfl_down(lp, off);
    }
    __shared__ float st[16], sl[16];
    int w = t >> 6, ln = t & 63;
    if (ln == 0) { st[w] = term; sl[w] = lp; }
    __syncthreads();
    if (t == 0) {
        float s = 0.f, l = 0.f;
#pragma unroll
        for (int i = 0; i < 16; ++i) { s += st[i]; l += sl[i]; }
        out[OFF_LOSS] = 1.25f * l * (1.0f / 2097152.0f);  // (1+beta)*mean
        out[OFF_PERP] = expf(-s);
    }
}

extern "C" void kernel_launch(void* const* d_in, const int* in_sizes, int n_in,
                              void* d_out, int out_size, void* d_ws, size_t ws_size,
                              hipStream_t stream) {
    const float* z   = (const float*)d_in[0];
    const float* emb = (const float*)d_in[1];
    float* out     = (float*)d_out;
    int*   hist    = (int*)d_ws;
    float* partial = (float*)((char*)d_ws + 4096);

    hipMemsetAsync(hist, 0, 4096, stream);
    vq_main<<<NBLK, TPB, 0, stream>>>(z, emb, hist, partial, out);
    vq_final<<<1, 1024, 0, stream>>>(hist, partial, out);
}

// Round 5
// 250.769 us; speedup vs baseline: 1.1866x; 1.1866x over previous
//
#include <hip/hip_runtime.h>
#include <cfloat>
#include <cstddef>

// VQ-VAE vector quantizer, MI355X / gfx950.
// z: (32, 64, 32, 32) f32 BCHW; embedding: (1024, 64) f32.
// Outputs concatenated f32: loss[1], z_q(BCHW)[2097152], perplexity[1],
// min_encodings[32768*1024], min_encoding_indices(as float)[32768].
//
// Structure history (measured):
//   R1 (108us): rows/lane resident, codes s_load-streamed (disjoint chunks)
//     -> SQC miss latency exposed, VALUBusy 37%.
//   R2 (284us): codes via uniform-addr vector loads -> 64x RF replication.
//   R3 (154us): codes resident, rows LDS-broadcast -> LDS return-bw bound
//     (broadcast b128 still writes 1KB RF / 8cyc; CU pipe 4x oversubscribed).
//   R4 (181us): rows scalar-streamed from BCHW -> 64 s_load_dword per row
//     (4KB channel stride) = SMEM issue storm.
//   R5 (this): NO broadcast anywhere. Lane (g,s) (g=lane>>2, s=lane&3) holds
//     slice s (channels c == s mod 4) of 8 resident codes (128 VGPR; block
//     covers all 1024). Rows staged in LDS slice-major; each lane reads only
//     its own 16-float slice (4x ds_read_b128, distinct addrs). 4-lane dot
//     combine via 2 DPP quad_perm adds (VALU-only). Per-row argmin: in-lane
//     8-code tree, 2 ds_swizzle xor stages on a (d_bits<<10)|j u64 key,
//     deferred block combine. Scan has ZERO vmem ops -> one-hot zero-fill
//     drains underneath (R1's proven trick).
//
// Numerics (must match the absmax-0.0 lineage bit-for-bit):
//   dot: lane s's fma chain over its 16 slice floats (k ascending) IS the
//     reference chain a_s; DPP stage1 (quad_perm[1,0,3,2]) gives a_s+a_{s^1},
//     stage2 (quad_perm[2,3,0,1]) gives (a0+a1)+(a2+a3) in all 4 lanes --
//     fp add commutes bitwise, so every lane holds the exact reference dot.
//     v_pk_fma_f32 pairs two CODES (chains independent) -- proven exact R2/R3.
//   e2: exact sequential double chain, computed in a tiny pre-kernel.
//   z2: R4-verbatim per-row sequential double chain.
//   d = (z2f + e2f) - 2.0f*dot (same two-rounding sequence; x2 is exact so
//     v_fma(-2,dot,t) == sub, either compilation identical).
//   argmin: in-lane tree pairs ascending j (strict < keeps lowest); cross-lane
//     via u64 key ((u64)bits(d)<<10)|j -- d = ~z2 >= 20 > 0 always (chi^2_64
//     row norms, |2dot| < 0.03), so bit order == value order and key order ==
//     (d, j) lexicographic == np.argmin first-index tie-break.
//   loss/zq/one-hot/final: R4 verbatim (bit-identical partial[512] tree).

#define NROWS 32768
#define NE    1024
#define EDIM  64
#define RPB   128
#define NBLK  (NROWS / RPB)   // 256 blocks = 1 per CU
#define TPB   512             // 8 waves
#define NPART 512

#define OFF_LOSS ((size_t)0)
#define OFF_ZQ   ((size_t)1)
#define OFF_PERP ((size_t)2097153)
#define OFF_OH   ((size_t)2097154)
#define OFF_IDX  ((size_t)35651586)

typedef float v2f __attribute__((ext_vector_type(2)));
typedef unsigned long long u64;

// ws layout (bytes): [0,4096) int hist[1024]; [4096,6144) float partial[512];
//                    [8192,12288) float e2buf[1024]

__global__ __launch_bounds__(128) void vq_e2(const float* __restrict__ emb,
                                             float* __restrict__ e2buf) {
    int j = blockIdx.x * 128 + threadIdx.x;          // grid 8x128 = 1024
    const float* e = emb + ((size_t)j << 6);
    double s = 0.0;
#pragma unroll
    for (int c = 0; c < EDIM; ++c) { float v = e[c]; s += (double)v * (double)v; }
    e2buf[j] = (float)s;
}

// DPP quad reduce: after this, all 4 lanes of each quad hold
// (a0+a1)+(a2+a3) exactly (0xB1 = quad_perm[1,0,3,2], 0x4E = [2,3,0,1]).
#define QRED(X) do {                                                           \
    int _q = __builtin_amdgcn_update_dpp(0, __float_as_int(X), 0xB1, 0xF, 0xF, true); \
    X += __int_as_float(_q);                                                   \
    _q = __builtin_amdgcn_update_dpp(0, __float_as_int(X), 0x4E, 0xF, 0xF, true);     \
    X += __int_as_float(_q); } while (0)

// ds_swizzle xor-lane min on a u64 key (BitMode: and=0x1F, xor in [14:10])
#define SWZMIN(IMM) do {                                                       \
    unsigned _lo = (unsigned)__builtin_amdgcn_ds_swizzle((int)key, IMM);       \
    unsigned _hi = (unsigned)__builtin_amdgcn_ds_swizzle((int)(key >> 32), IMM); \
    u64 _o = ((u64)_hi << 32) | _lo;                                           \
    if (_o < key) key = _o; } while (0)

__global__ __launch_bounds__(TPB, 2) void vq_main(const float* __restrict__ z,
                                                  const float* __restrict__ emb,
                                                  const float* __restrict__ e2buf,
                                                  int* __restrict__ hist,
                                                  float* __restrict__ partial,
                                                  float* __restrict__ out) {
    const int t    = threadIdx.x;
    const int lane = t & 63;
    const int q    = t >> 6;          // wave id 0..7
    const int g    = lane >> 2;       // group 0..15 within wave
    const int s    = lane & 3;        // channel slice 0..3 (c == s mod 4)
    const int r0   = blockIdx.x * RPB;
    const int b    = r0 >> 10;        // 128 | 1024 -> single batch per block
    const int m0   = r0 & 1023;
    const size_t zb0 = (size_t)b * 65536 + (size_t)m0;

    __shared__ float zs[RPB][80];     // slice-major rows: z[r][c] at
                                      // [r][20*(c&3) + (c>>2)]  (40 KB)
    __shared__ float s_z2[RPB];
    __shared__ u64   s_cand[32][RPB]; // 4 candidates x 8 waves   (32 KB)
    __shared__ int   s_idx[RPB];
    __shared__ float s_l2[2][8];

    // ---- stage 128 z-rows into LDS slice-major (coalesced global reads) ---
#pragma unroll
    for (int it = 0; it < 4; ++it) {
        int i  = t + it * TPB;        // 0..2047
        int c  = i >> 5;              // channel 0..63
        int f4 = i & 31;              // row group
        float4 v = *(const float4*)(z + zb0 + (size_t)c * 1024 + 4 * f4);
        int col = 20 * (c & 3) + (c >> 2);
        zs[4 * f4 + 0][col] = v.x;
        zs[4 * f4 + 1][col] = v.y;
        zs[4 * f4 + 2][col] = v.z;
        zs[4 * f4 + 3][col] = v.w;
    }

    // ---- ||z_r||^2 (R4 verbatim: sequential double chain, one rounding) ---
    if (t < RPB) {
        const float* zr = z + zb0 + t;
        double sd = 0.0;
#pragma unroll
        for (int c = 0; c < EDIM; ++c) {
            float v = zr[(size_t)c << 10];
            sd += (double)v * (double)v;
        }
        s_z2[t] = (float)sd;
    }

    // ---- resident codebook slices: 8 codes/lane as 4 code-pair v2f chains --
    // wave q, group g covers codes j = 128q + g + 16i, i=0..7 (pair i=2m,2m+1)
    const int jb = (q << 7) + g;
    v2f epk0[16], epk1[16], epk2[16], epk3[16];
    float e2r[8];
    {
        const float* ebase = emb;
#pragma unroll
        for (int mp = 0; mp < 4; ++mp) {
            int ja = jb + 32 * mp;        // code i=2mp
            int jc = ja + 16;             // code i=2mp+1
            const float* ea = ebase + ((size_t)ja << 6) + s;
            const float* ec = ebase + ((size_t)jc << 6) + s;
            v2f* dst = (mp == 0) ? epk0 : (mp == 1) ? epk1 : (mp == 2) ? epk2 : epk3;
#pragma unroll
            for (int kp = 0; kp < 16; ++kp) {
                float fa = ea[4 * kp];    // e[ja][4kp + s]
                float fc = ec[4 * kp];
                dst[kp] = (v2f){fa, fc};
            }
            e2r[2 * mp]     = e2buf[ja];
            e2r[2 * mp + 1] = e2buf[jc];
        }
    }

    // drain all staging loads BEFORE issuing the zero-fill stores, so no
    // later vmcnt wait ever has the stores older-or-mixed in its count
    asm volatile("s_waitcnt vmcnt(0)" ::: "memory");

    // ---- fire-and-forget zero-fill of this block's one-hot slab ----------
    // 128 rows x 4KB contiguous. The scan below has ZERO vmem ops (LDS+VALU
    // only) and the mid barrier waits lgkm only -> stores drain under ~35us
    // of compute; the post-scan __syncthreads (vmcnt0) orders the 1.0f scatter.
    {
        float* ohb = out + OFF_OH + (size_t)r0 * 1024;   // 131072 floats
        if (t == 0) {
            *(float2*)ohb              = make_float2(0.f, 0.f);
            *(float2*)(ohb + 131070)   = make_float2(0.f, 0.f);
        }
        float4* p4 = (float4*)(ohb + 2);                 // 16B-aligned
        const float4 z4 = make_float4(0.f, 0.f, 0.f, 0.f);
        for (int i = t; i < 32767; i += TPB) p4[i] = z4;
    }

    // raw barrier: LDS producers flushed, vmem stores stay in flight
    asm volatile("s_waitcnt lgkmcnt(0)" ::: "memory");
    __builtin_amdgcn_s_barrier();

    // ---- scan: 128 rows; per row each lane covers its 8 resident codes ----
    for (int r = 0; r < RPB; ++r) {
        const float4* zp4 = (const float4*)(&zs[r][s * 20]);  // own slice only
        float4 zA = zp4[0], zB = zp4[1], zC = zp4[2], zD = zp4[3];
        float zrow2 = s_z2[r];

        v2f p0 = {0.f, 0.f}, p1 = {0.f, 0.f}, p2 = {0.f, 0.f}, p3 = {0.f, 0.f};
        float zsl[16] = {zA.x, zA.y, zA.z, zA.w,  zB.x, zB.y, zB.z, zB.w,
                         zC.x, zC.y, zC.z, zC.w,  zD.x, zD.y, zD.z, zD.w};
#pragma unroll
        for (int kp = 0; kp < 16; ++kp) {
            v2f zz = {zsl[kp], zsl[kp]};
            p0 = __builtin_elementwise_fma(epk0[kp], zz, p0);  // v_pk_fma_f32
            p1 = __builtin_elementwise_fma(epk1[kp], zz, p1);
            p2 = __builtin_elementwise_fma(epk2[kp], zz, p2);
            p3 = __builtin_elementwise_fma(epk3[kp], zz, p3);
        }
        // 4-lane quad combine: every lane gets exact (a0+a1)+(a2+a3) per code
        float d0 = p0.x, d1 = p0.y, d2 = p1.x, d3 = p1.y;
        float d4 = p2.x, d5 = p2.y, d6 = p3.x, d7 = p3.y;
        QRED(d0); QRED(d1); QRED(d2); QRED(d3);
        QRED(d4); QRED(d5); QRED(d6); QRED(d7);
        // distances, reference rounding: fl( fl(z2+e2) - 2*dot )
        d0 = (zrow2 + e2r[0]) - 2.0f * d0;
        d1 = (zrow2 + e2r[1]) - 2.0f * d1;
        d2 = (zrow2 + e2r[2]) - 2.0f * d2;
        d3 = (zrow2 + e2r[3]) - 2.0f * d3;
        d4 = (zrow2 + e2r[4]) - 2.0f * d4;
        d5 = (zrow2 + e2r[5]) - 2.0f * d5;
        d6 = (zrow2 + e2r[6]) - 2.0f * d6;
        d7 = (zrow2 + e2r[7]) - 2.0f * d7;
        // in-lane tree, j = jb + 16*i ascending in i: strict < = first index
        float ea_ = (d1 < d0) ? d1 : d0;  int ma_ = (d1 < d0) ? 1 : 0;
        float eb_ = (d3 < d2) ? d3 : d2;  int mb_ = (d3 < d2) ? 3 : 2;
        float ec_ = (d5 < d4) ? d5 : d4;  int mc_ = (d5 < d4) ? 5 : 4;
        float ed_ = (d7 < d6) ? d7 : d6;  int md_ = (d7 < d6) ? 7 : 6;
        float fa_ = (eb_ < ea_) ? eb_ : ea_;  int na_ = (eb_ < ea_) ? mb_ : ma_;
        float fb_ = (ed_ < ec_) ? ed_ : ec_;  int nb_ = (ed_ < ec_) ? md_ : mc_;
        float dw  = (fb_ < fa_) ? fb_ : fa_;  int mw  = (fb_ < fa_) ? nb_ : na_;
        int   jw  = jb + (mw << 4);
        // cross-group xor reduce on (d,j)-lex key; d>0 -> bit order == order
        u64 key = ((u64)__float_as_uint(dw) << 10) | (unsigned)jw;
        SWZMIN(0x101F);   // xor lane 4  (group ^ 1)
        SWZMIN(0x201F);   // xor lane 8  (group ^ 2)
        if ((lane & 15) == 0)
            s_cand[(q << 2) + (lane >> 4)][r] = key;   // 4 cands per wave
    }
    __syncthreads();   // full barrier: vmcnt(0) -> zero-fill globally visible

    // ---- combine 32 candidates per row; u64 key handles d-tie -> min j ----
    if (t < RPB) {
        u64 bk = s_cand[0][t];
#pragma unroll
        for (int w = 1; w < 32; ++w) {
            u64 kw = s_cand[w][t];
            if (kw < bk) bk = kw;     // strict <: keys unique per j
        }
        int bj = (int)(bk & 1023u);
        s_idx[t] = bj;
        out[OFF_IDX + (size_t)(r0 + t)] = (float)bj;
        out[OFF_OH + (size_t)(r0 + t) * 1024 + bj] = 1.0f;
        atomicAdd(&hist[bj], 1);
    }
    __syncthreads();

    // ---- z_q (straight-through) + loss partials (R1/R4-exact trees) -------
    {
        const int gg  = q & 1;
        const int c0  = q >> 1;
        const int r   = (gg << 6) + lane;
        const int grow = r0 + r;
        const int bb  = grow >> 10;
        const int mm  = grow & 1023;
        const size_t zbr = (size_t)bb * 65536 + (size_t)mm;
        const int    jjx = s_idx[r];
        const float* er  = emb + ((size_t)jjx << 6);
        float* zq = out + OFF_ZQ + zbr;
        float lA = 0.f, lB = 0.f;
#pragma unroll
        for (int i = 0; i < 8; ++i) {
            int c = c0 + 8 * i;
            float zc   = z[zbr + (size_t)c * 1024];
            float ev   = er[c];
            float diff = ev - zc;
            zq[(size_t)c * 1024] = zc + diff;           // zp + (z_q - zp)
            lA = fmaf(diff, diff, lA);
        }
#pragma unroll
        for (int i = 0; i < 8; ++i) {
            int c = (c0 + 4) + 8 * i;
            float zc   = z[zbr + (size_t)c * 1024];
            float ev   = er[c];
            float diff = ev - zc;
            zq[(size_t)c * 1024] = zc + diff;
            lB = fmaf(diff, diff, lB);
        }
#pragma unroll
        for (int off = 32; off >= 1; off >>= 1) {
            lA += __shfl_down(lA, off);
            lB += __shfl_down(lB, off);
        }
        if (lane == 0) { s_l2[gg][c0] = lA; s_l2[gg][c0 + 4] = lB; }
        __syncthreads();
        if (t == 0) {
            float sA = 0.f, sB = 0.f;
#pragma unroll
            for (int c = 0; c < 8; ++c) {   // ascending class, as in R1
                sA += s_l2[0][c];
                sB += s_l2[1][c];
            }
            partial[2 * blockIdx.x + 0] = sA;
            partial[2 * blockIdx.x + 1] = sB;
        }
    }
}

__global__ __launch_bounds__(1024) void vq_final(const int* __restrict__ hist,
                                                 const float* __restrict__ partial,
                                                 float* __restrict__ out) {
    int t = threadIdx.x;
    float p    = (float)hist[t] * (1.0f / 32768.0f);
    float term = p * logf(p + 1e-10f);
    float lp   = (t < NPART) ? partial[t] : 0.f;
#pragma unroll
    for (int off = 32; off >= 1; off >>= 1) {
        term += __shfl_down(term, off);
        lp   += __shfl_down(lp, off);
    }
    __shared__ float st[16], sl[16];
    int w = t >> 6, ln = t & 63;
    if (ln == 0) { st[w] = term; sl[w] = lp; }
    __syncthreads();
    if (t == 0) {
        float s = 0.f, l = 0.f;
#pragma unroll
        for (int i = 0; i < 16; ++i) { s += st[i]; l += sl[i]; }
        out[OFF_LOSS] = 1.25f * l * (1.0f / 2097152.0f);  // (1+beta)*mean
        out[OFF_PERP] = expf(-s);
    }
}

extern "C" void kernel_launch(void* const* d_in, const int* in_sizes, int n_in,
                              void* d_out, int out_size, void* d_ws, size_t ws_size,
                              hipStream_t stream) {
    const float* z   = (const float*)d_in[0];
    const float* emb = (const float*)d_in[1];
    float* out     = (float*)d_out;
    int*   hist    = (int*)d_ws;
    float* partial = (float*)((char*)d_ws + 4096);
    float* e2buf   = (float*)((char*)d_ws + 8192);

    hipMemsetAsync(hist, 0, 4096, stream);
    vq_e2<<<8, 128, 0, stream>>>(emb, e2buf);
    vq_main<<<NBLK, TPB, 0, stream>>>(z, emb, e2buf, hist, partial, out);
    vq_final<<<1, 1024, 0, stream>>>(hist, partial, out);
}